// Round 5
// baseline (194.417 us; speedup 1.0000x reference)
//
#include <hip/hip_runtime.h>
#include <math.h>

// Analytic inverse of [[R, t],[0,0,0,1]] where R comes from a normalized quat:
// inv = [[R^T, -R^T t],[0,0,0,1]].
struct Inv {
    float i00, i01, i02, it0;
    float i10, i11, i12, it1;
    float i20, i21, i22, it2;
};

__device__ __forceinline__ Inv make_inv(const float* __restrict__ q,
                                        const float* __restrict__ t, int b) {
    float w = q[b * 4 + 0], x = q[b * 4 + 1], y = q[b * 4 + 2], z = q[b * 4 + 3];
    float inv_n = 1.0f / sqrtf(w * w + x * x + y * y + z * z);
    w *= inv_n; x *= inv_n; y *= inv_n; z *= inv_n;
    float R00 = 1.f - 2.f * y * y - 2.f * z * z;
    float R01 = 2.f * x * y - 2.f * z * w;
    float R02 = 2.f * x * z + 2.f * y * w;
    float R10 = 2.f * x * y + 2.f * z * w;
    float R11 = 1.f - 2.f * x * x - 2.f * z * z;
    float R12 = 2.f * y * z - 2.f * x * w;
    float R20 = 2.f * x * z - 2.f * y * w;
    float R21 = 2.f * y * z + 2.f * x * w;
    float R22 = 1.f - 2.f * x * x - 2.f * y * y;
    float t0 = t[b * 3 + 0], t1 = t[b * 3 + 1], t2 = t[b * 3 + 2];
    Inv v;
    v.i00 = R00; v.i01 = R10; v.i02 = R20; v.it0 = -(R00 * t0 + R10 * t1 + R20 * t2);
    v.i10 = R01; v.i11 = R11; v.i12 = R21; v.it1 = -(R01 * t0 + R11 * t1 + R21 * t2);
    v.i20 = R02; v.i21 = R12; v.i22 = R22; v.it2 = -(R02 * t0 + R12 * t1 + R22 * t2);
    return v;
}

__device__ __forceinline__ void xf(const Inv& M, float px, float py, float pz,
                                   float& ox, float& oy, float& oz) {
    ox = fmaf(M.i00, px, fmaf(M.i01, py, fmaf(M.i02, pz, M.it0)));
    oy = fmaf(M.i10, px, fmaf(M.i11, py, fmaf(M.i12, pz, M.it1)));
    oz = fmaf(M.i20, px, fmaf(M.i21, py, fmaf(M.i22, pz, M.it2)));
}

// Non-temporal float4 store (measured neutral in R4; kept — output is
// write-once, never re-read by the kernel).
using nat_f4 = __attribute__((ext_vector_type(4))) float;
__device__ __forceinline__ void store_nt(float4* p, const float4& v) {
    __builtin_nontemporal_store(*(const nat_f4*)&v, (nat_f4*)p);
}

// ROUND 5 — falsification experiment: pure streaming, NO LDS, NO barriers.
//
// History: R0 (8192 short blocks, full vmcnt drains), R1 (2048 persistent
// blocks, counted vmcnt, lgkm-only barriers), R4 (+ NT stores) all measure
// EXACTLY ~61 us = 2.47 TB/s pin vs a 6.3 TB/s copy / 6.8 TB/s fill ceiling
// measured on the same part. The single invariant across all three is the
// barrier-synchronized LDS round trip. This kernel removes it entirely.
//
// Mechanism: a thread that loads 3 CONSECUTIVE float4 (48 B) holds exactly
// 4 complete points (words 12T..12T+11) with the same component phasing the
// old compute phase used — no cross-thread exchange needed at all. The lane
// address pattern is 48 B-strided (each wave load touches 48 lines/KB vs 16
// coalesced), but the 3 loads jointly cover a contiguous 3 KB per wave and
// lines are L1-hot across the triple: bounded extra L1 lookup cost (~7 us
// worst case, hidden), in exchange for zero sync and free compiler
// scheduling of 3 independent loads -> 12 FMA triplets -> 3 stores.
//
// If this also lands at ~61 us, the wall is the memory system on this mixed
// 96R+96W stream and ~61 us is the documented roofline.
__global__ __launch_bounds__(256) void realign_stream_kernel(
        const float4* __restrict__ pcd,
        const float* __restrict__ T_mis,
        const float* __restrict__ q,
        const float* __restrict__ t,
        float* __restrict__ out_mat,
        float4* __restrict__ out_pcd,
        int f4_per_batch) {
    const int b = blockIdx.y;
    const int tid = threadIdx.x;

    // Each thread owns 3 consecutive float4 = 4 complete points.
    const size_t base = (size_t)b * (size_t)f4_per_batch
                      + (size_t)blockIdx.x * 768u + (size_t)tid * 3u;

    const float4 v0 = pcd[base + 0];
    const float4 v1 = pcd[base + 1];
    const float4 v2 = pcd[base + 2];

    const Inv M = make_inv(q, t, b);   // b wave-uniform -> scalarizes

    // Fused tmat: batch_T_pred[b] = inv_T[b] @ T_mis[b] (once per batch).
    if (blockIdx.x == 0 && tid < 16) {
        const int i = tid >> 2;
        const int j = tid & 3;
        const float* Tb = T_mis + b * 16;
        float val;
        if (i < 3) {
            float a0, a1, a2, it;
            if (i == 0)      { a0 = M.i00; a1 = M.i01; a2 = M.i02; it = M.it0; }
            else if (i == 1) { a0 = M.i10; a1 = M.i11; a2 = M.i12; it = M.it1; }
            else             { a0 = M.i20; a1 = M.i21; a2 = M.i22; it = M.it2; }
            val = fmaf(a0, Tb[0 * 4 + j],
                  fmaf(a1, Tb[1 * 4 + j],
                  fmaf(a2, Tb[2 * 4 + j],
                       it * Tb[3 * 4 + j])));
        } else {
            val = Tb[3 * 4 + j];
        }
        out_mat[b * 16 + tid] = val;
    }

    // 4 points, component layout: v0=(x0,y0,z0,x1) v1=(y1,z1,x2,y2) v2=(z2,x3,y3,z3)
    float4 o0, o1, o2;
    xf(M, v0.x, v0.y, v0.z, o0.x, o0.y, o0.z);
    xf(M, v0.w, v1.x, v1.y, o0.w, o1.x, o1.y);
    xf(M, v1.z, v1.w, v2.x, o1.z, o1.w, o2.x);
    xf(M, v2.y, v2.z, v2.w, o2.y, o2.z, o2.w);

    store_nt(&out_pcd[base + 0], o0);
    store_nt(&out_pcd[base + 1], o1);
    store_nt(&out_pcd[base + 2], o2);
}

extern "C" void kernel_launch(void* const* d_in, const int* in_sizes, int n_in,
                              void* d_out, int out_size, void* d_ws, size_t ws_size,
                              hipStream_t stream) {
    const float* pcd   = (const float*)d_in[0];  // (B, N, 3)
    const float* T_mis = (const float*)d_in[1];  // (B, 4, 4)
    const float* q     = (const float*)d_in[2];  // (B, 4)
    const float* t     = (const float*)d_in[3];  // (B, 3)
    float* out = (float*)d_out;

    const int B = in_sizes[2] / 4;                            // 32
    const long long N = (long long)in_sizes[0] / (3LL * B);   // 262144
    const int f4_per_batch = (int)(3 * N / 4);                // 196608
    const int blocks_x = f4_per_batch / 768;                  // 256 (exact)

    // Output layout: [0, B*16) = batch_T_pred; then pcd_new (float4-aligned).
    dim3 grid(blocks_x, B);
    realign_stream_kernel<<<grid, 256, 0, stream>>>(
        (const float4*)pcd, T_mis, q, t,
        out, (float4*)(out + B * 16), f4_per_batch);
}

// Round 6
// 174.819 us; speedup vs baseline: 1.1121x; 1.1121x over previous
//
#include <hip/hip_runtime.h>
#include <math.h>

// Analytic inverse of [[R, t],[0,0,0,1]] where R comes from a normalized quat:
// inv = [[R^T, -R^T t],[0,0,0,1]].
struct Inv {
    float i00, i01, i02, it0;
    float i10, i11, i12, it1;
    float i20, i21, i22, it2;
};

__device__ __forceinline__ Inv make_inv(const float* __restrict__ q,
                                        const float* __restrict__ t, int b) {
    float w = q[b * 4 + 0], x = q[b * 4 + 1], y = q[b * 4 + 2], z = q[b * 4 + 3];
    float inv_n = 1.0f / sqrtf(w * w + x * x + y * y + z * z);
    w *= inv_n; x *= inv_n; y *= inv_n; z *= inv_n;
    float R00 = 1.f - 2.f * y * y - 2.f * z * z;
    float R01 = 2.f * x * y - 2.f * z * w;
    float R02 = 2.f * x * z + 2.f * y * w;
    float R10 = 2.f * x * y + 2.f * z * w;
    float R11 = 1.f - 2.f * x * x - 2.f * z * z;
    float R12 = 2.f * y * z - 2.f * x * w;
    float R20 = 2.f * x * z - 2.f * y * w;
    float R21 = 2.f * y * z + 2.f * x * w;
    float R22 = 1.f - 2.f * x * x - 2.f * y * y;
    float t0 = t[b * 3 + 0], t1 = t[b * 3 + 1], t2 = t[b * 3 + 2];
    Inv v;
    v.i00 = R00; v.i01 = R10; v.i02 = R20; v.it0 = -(R00 * t0 + R10 * t1 + R20 * t2);
    v.i10 = R01; v.i11 = R11; v.i12 = R21; v.it1 = -(R01 * t0 + R11 * t1 + R21 * t2);
    v.i20 = R02; v.i21 = R12; v.i22 = R22; v.it2 = -(R02 * t0 + R12 * t1 + R22 * t2);
    return v;
}

__device__ __forceinline__ void xf(const Inv& M, float px, float py, float pz,
                                   float& ox, float& oy, float& oz) {
    ox = fmaf(M.i00, px, fmaf(M.i01, py, fmaf(M.i02, pz, M.it0)));
    oy = fmaf(M.i10, px, fmaf(M.i11, py, fmaf(M.i12, pz, M.it1)));
    oz = fmaf(M.i20, px, fmaf(M.i21, py, fmaf(M.i22, pz, M.it2)));
}

// Barrier that drains ONLY lgkmcnt (LDS), NOT vmcnt (see Round-1 notes).
__device__ __forceinline__ void bar_lgkm() {
    asm volatile("s_waitcnt lgkmcnt(0)\n\ts_barrier" ::: "memory");
}

using nat_f4 = __attribute__((ext_vector_type(4))) float;
// NT store: proven NEUTRAL in R4 (kept; output is write-once).
__device__ __forceinline__ void store_nt(float4* p, const float4& v) {
    __builtin_nontemporal_store(*(const nat_f4*)&v, (nat_f4*)p);
}
// ROUND 6 VARIABLE — NT load (global_load_dwordx4 ... nt).
// Evidence so far: R1/R4 (coalesced+LDS) and R5 (strided, zero-sync) all run
// at a CONSTANT ~2.5 TB/s of HBM-counted traffic (fill sustains 6.7, copy
// ubench 6.3 on the same part), and FETCH_SIZE is EXACTLY half the 96 MB
// input every round -> the read stream alternates L3-hit / HBM-miss at fine
// grain. Theory: this hit/miss interleave throttles the read path (shared
// TCC pipeline w/ limited outstanding misses) and punches holes in the
// DRAM-side read stream (poor row locality vs a clean full stream).
// NT loads bypass L3 retention: full 96 MB streams from HBM each replay as a
// hole-free sequential stream, and stops thrashing L3 between replays.
__device__ __forceinline__ float4 load_nt(const float4* p) {
    nat_f4 v = __builtin_nontemporal_load((const nat_f4*)p);
    float4 r; *(nat_f4*)&r = v; return r;
}

// Persistent pipelined structure (identical to R1/R4 for single-variable A/B):
//  - grid = 64 x 32 = 2048 blocks (persistent, 4 chunks of 768 float4 each);
//  - chunk i+1's 3 global loads issued at top of iter i, consumed after the
//    store phase (counted vmcnt, stores stay in flight);
//  - 2 lgkm-only barriers per iteration, single 12 KB LDS buffer;
//  - LDS compute-phase stride 12 words/lane -> conflict-free ds_read_b128.
__global__ __launch_bounds__(256) void realign_fused_kernel(
        const float4* __restrict__ pcd,
        const float* __restrict__ T_mis,
        const float* __restrict__ q,
        const float* __restrict__ t,
        float* __restrict__ out_mat,
        float4* __restrict__ out_pcd,
        int f4_per_batch, int stride_f4, int n_iters) {
    __shared__ float4 smem[768];   // 12 KB
    const int b = blockIdx.y;
    const int tid = threadIdx.x;

    size_t base = (size_t)b * (size_t)f4_per_batch + (size_t)blockIdx.x * 768u;

    // Prologue: load + stage chunk 0 (b is wave-uniform -> make_inv scalarizes).
    float4 r0 = load_nt(&pcd[base + tid]);
    float4 r1 = load_nt(&pcd[base + 256 + tid]);
    float4 r2 = load_nt(&pcd[base + 512 + tid]);

    const Inv M = make_inv(q, t, b);

    // Fused tmat: batch_T_pred[b] = inv_T[b] @ T_mis[b] (once per batch).
    if (blockIdx.x == 0 && tid < 16) {
        const int i = tid >> 2;
        const int j = tid & 3;
        const float* Tb = T_mis + b * 16;
        float val;
        if (i < 3) {
            float a0, a1, a2, it;
            if (i == 0)      { a0 = M.i00; a1 = M.i01; a2 = M.i02; it = M.it0; }
            else if (i == 1) { a0 = M.i10; a1 = M.i11; a2 = M.i12; it = M.it1; }
            else             { a0 = M.i20; a1 = M.i21; a2 = M.i22; it = M.it2; }
            val = fmaf(a0, Tb[0 * 4 + j],
                  fmaf(a1, Tb[1 * 4 + j],
                  fmaf(a2, Tb[2 * 4 + j],
                       it * Tb[3 * 4 + j])));
        } else {
            val = Tb[3 * 4 + j];
        }
        out_mat[b * 16 + tid] = val;
    }

    smem[tid]       = r0;
    smem[256 + tid] = r1;
    smem[512 + tid] = r2;
    bar_lgkm();

    for (int it = 0; it < n_iters; ++it) {
        // Prefetch chunk it+1 into registers.
        float4 n0{}, n1{}, n2{};
        const bool has_next = (it + 1 < n_iters);
        if (has_next) {
            const size_t nb = base + (size_t)stride_f4;
            n0 = load_nt(&pcd[nb + tid]);
            n1 = load_nt(&pcd[nb + 256 + tid]);
            n2 = load_nt(&pcd[nb + 512 + tid]);
        }

        // Compute chunk `it` in place (each thread owns slots 3t..3t+2).
        float4 v0 = smem[3 * tid + 0];
        float4 v1 = smem[3 * tid + 1];
        float4 v2 = smem[3 * tid + 2];
        float4 o0, o1, o2;
        xf(M, v0.x, v0.y, v0.z, o0.x, o0.y, o0.z);
        xf(M, v0.w, v1.x, v1.y, o0.w, o1.x, o1.y);
        xf(M, v1.z, v1.w, v2.x, o1.z, o1.w, o2.x);
        xf(M, v2.y, v2.z, v2.w, o2.y, o2.z, o2.w);
        smem[3 * tid + 0] = o0;
        smem[3 * tid + 1] = o1;
        smem[3 * tid + 2] = o2;
        bar_lgkm();   // compute-writes visible to store-phase readers

        // Coalesced LDS -> global NT stores, then restage chunk it+1 into the
        // SAME slots (same thread, same address: in-order per wave, no
        // barrier needed between the read and the write).
        float4 s0 = smem[tid];
        float4 s1 = smem[256 + tid];
        float4 s2 = smem[512 + tid];
        store_nt(&out_pcd[base + tid],       s0);
        store_nt(&out_pcd[base + 256 + tid], s1);
        store_nt(&out_pcd[base + 512 + tid], s2);
        if (has_next) {
            smem[tid]       = n0;
            smem[256 + tid] = n1;
            smem[512 + tid] = n2;
        }
        bar_lgkm();   // restage-writes visible to next iteration's compute

        base += (size_t)stride_f4;
    }
}

extern "C" void kernel_launch(void* const* d_in, const int* in_sizes, int n_in,
                              void* d_out, int out_size, void* d_ws, size_t ws_size,
                              hipStream_t stream) {
    const float* pcd   = (const float*)d_in[0];  // (B, N, 3)
    const float* T_mis = (const float*)d_in[1];  // (B, 4, 4)
    const float* q     = (const float*)d_in[2];  // (B, 4)
    const float* t     = (const float*)d_in[3];  // (B, 3)
    float* out = (float*)d_out;

    const int B = in_sizes[2] / 4;                            // 32
    const long long N = (long long)in_sizes[0] / (3LL * B);   // 262144
    const int f4_per_batch = (int)(3 * N / 4);                // 196608
    const int chunks = f4_per_batch / 768;                    // 256

    // 4 chunks per block -> 64 x 32 = 2048 blocks, persistent, no tail.
    int iters = 4;
    if (chunks % 4 != 0) iters = (chunks % 2 == 0) ? 2 : 1;
    const int blocks_x = chunks / iters;                      // 64
    const int stride_f4 = blocks_x * 768;

    // Output layout: [0, B*16) = batch_T_pred; then pcd_new (float4-aligned).
    dim3 grid(blocks_x, B);
    realign_fused_kernel<<<grid, 256, 0, stream>>>(
        (const float4*)pcd, T_mis, q, t,
        out, (float4*)(out + B * 16), f4_per_batch, stride_f4, iters);
}

// Round 7
// 174.227 us; speedup vs baseline: 1.1159x; 1.0034x over previous
//
#include <hip/hip_runtime.h>
#include <math.h>

// Analytic inverse of [[R, t],[0,0,0,1]] where R comes from a normalized quat:
// inv = [[R^T, -R^T t],[0,0,0,1]].
struct Inv {
    float i00, i01, i02, it0;
    float i10, i11, i12, it1;
    float i20, i21, i22, it2;
};

__device__ __forceinline__ Inv make_inv(const float* __restrict__ q,
                                        const float* __restrict__ t, int b) {
    float w = q[b * 4 + 0], x = q[b * 4 + 1], y = q[b * 4 + 2], z = q[b * 4 + 3];
    float inv_n = 1.0f / sqrtf(w * w + x * x + y * y + z * z);
    w *= inv_n; x *= inv_n; y *= inv_n; z *= inv_n;
    float R00 = 1.f - 2.f * y * y - 2.f * z * z;
    float R01 = 2.f * x * y - 2.f * z * w;
    float R02 = 2.f * x * z + 2.f * y * w;
    float R10 = 2.f * x * y + 2.f * z * w;
    float R11 = 1.f - 2.f * x * x - 2.f * z * z;
    float R12 = 2.f * y * z - 2.f * x * w;
    float R20 = 2.f * x * z - 2.f * y * w;
    float R21 = 2.f * y * z + 2.f * x * w;
    float R22 = 1.f - 2.f * x * x - 2.f * y * y;
    float t0 = t[b * 3 + 0], t1 = t[b * 3 + 1], t2 = t[b * 3 + 2];
    Inv v;
    v.i00 = R00; v.i01 = R10; v.i02 = R20; v.it0 = -(R00 * t0 + R10 * t1 + R20 * t2);
    v.i10 = R01; v.i11 = R11; v.i12 = R21; v.it1 = -(R01 * t0 + R11 * t1 + R21 * t2);
    v.i20 = R02; v.i21 = R12; v.i22 = R22; v.it2 = -(R02 * t0 + R12 * t1 + R22 * t2);
    return v;
}

__device__ __forceinline__ void xf(const Inv& M, float px, float py, float pz,
                                   float& ox, float& oy, float& oz) {
    ox = fmaf(M.i00, px, fmaf(M.i01, py, fmaf(M.i02, pz, M.it0)));
    oy = fmaf(M.i10, px, fmaf(M.i11, py, fmaf(M.i12, pz, M.it1)));
    oz = fmaf(M.i20, px, fmaf(M.i21, py, fmaf(M.i22, pz, M.it2)));
}

// Barrier that drains ONLY lgkmcnt (LDS), NOT vmcnt (see Round-1 notes).
__device__ __forceinline__ void bar_lgkm() {
    asm volatile("s_waitcnt lgkmcnt(0)\n\ts_barrier" ::: "memory");
}

using nat_f4 = __attribute__((ext_vector_type(4))) float;

// NT LOAD — KEPT (Round-6 win: kernel ~61.2 -> ~56.6 us, byte rate 2.4 ->
// 3.4 TB/s). The harness's 2x403 MB fill dispatches flush L3 every replay,
// so the input can never stay L3-resident: bypassing L3 retention gives a
// clean, hole-free HBM read stream instead of a half-hit/half-miss
// interleave (FETCH_SIZE was pinned at exactly input/2 for R0-R5).
__device__ __forceinline__ float4 load_nt(const float4* p) {
    nat_f4 v = __builtin_nontemporal_load((const nat_f4*)p);
    float4 r; *(nat_f4*)&r = v; return r;
}

// ROUND 7 VARIABLE — stores reverted to CACHED (NT stores removed).
// Rationale: the 6.8 TB/s fill and 6.3 TB/s copy comparators both use
// CACHED writes: L2 accumulates full dirty lines and writes back in
// address-ordered bursts (good DRAM row locality). Our `nt` stores bypass
// that batching and reach HBM in scattered wave-issue order. R4 measured
// NT stores neutral, but that was in the 2.4 TB/s regime where the dirty
// read interleave was binding; with reads now clean (NT), the store path
// is the prime suspect for the remaining 1.8x gap. Bonus: with NT loads no
// longer allocating in L3, the 98 MB output can land in L3 and write back
// lazily (input/output no longer compete for L3 as in R1).

// Persistent pipelined structure (identical to R1/R4/R6):
//  - grid = 64 x 32 = 2048 blocks (persistent, 4 chunks of 768 float4 each);
//  - chunk i+1's 3 global loads issued at top of iter i, consumed after the
//    store phase (counted vmcnt, stores stay in flight);
//  - 2 lgkm-only barriers per iteration, single 12 KB LDS buffer;
//  - LDS compute-phase stride 12 words/lane -> conflict-free ds_read_b128.
__global__ __launch_bounds__(256) void realign_fused_kernel(
        const float4* __restrict__ pcd,
        const float* __restrict__ T_mis,
        const float* __restrict__ q,
        const float* __restrict__ t,
        float* __restrict__ out_mat,
        float4* __restrict__ out_pcd,
        int f4_per_batch, int stride_f4, int n_iters) {
    __shared__ float4 smem[768];   // 12 KB
    const int b = blockIdx.y;
    const int tid = threadIdx.x;

    size_t base = (size_t)b * (size_t)f4_per_batch + (size_t)blockIdx.x * 768u;

    // Prologue: load + stage chunk 0 (b is wave-uniform -> make_inv scalarizes).
    float4 r0 = load_nt(&pcd[base + tid]);
    float4 r1 = load_nt(&pcd[base + 256 + tid]);
    float4 r2 = load_nt(&pcd[base + 512 + tid]);

    const Inv M = make_inv(q, t, b);

    // Fused tmat: batch_T_pred[b] = inv_T[b] @ T_mis[b] (once per batch).
    if (blockIdx.x == 0 && tid < 16) {
        const int i = tid >> 2;
        const int j = tid & 3;
        const float* Tb = T_mis + b * 16;
        float val;
        if (i < 3) {
            float a0, a1, a2, it;
            if (i == 0)      { a0 = M.i00; a1 = M.i01; a2 = M.i02; it = M.it0; }
            else if (i == 1) { a0 = M.i10; a1 = M.i11; a2 = M.i12; it = M.it1; }
            else             { a0 = M.i20; a1 = M.i21; a2 = M.i22; it = M.it2; }
            val = fmaf(a0, Tb[0 * 4 + j],
                  fmaf(a1, Tb[1 * 4 + j],
                  fmaf(a2, Tb[2 * 4 + j],
                       it * Tb[3 * 4 + j])));
        } else {
            val = Tb[3 * 4 + j];
        }
        out_mat[b * 16 + tid] = val;
    }

    smem[tid]       = r0;
    smem[256 + tid] = r1;
    smem[512 + tid] = r2;
    bar_lgkm();

    for (int it = 0; it < n_iters; ++it) {
        // Prefetch chunk it+1 into registers.
        float4 n0{}, n1{}, n2{};
        const bool has_next = (it + 1 < n_iters);
        if (has_next) {
            const size_t nb = base + (size_t)stride_f4;
            n0 = load_nt(&pcd[nb + tid]);
            n1 = load_nt(&pcd[nb + 256 + tid]);
            n2 = load_nt(&pcd[nb + 512 + tid]);
        }

        // Compute chunk `it` in place (each thread owns slots 3t..3t+2).
        float4 v0 = smem[3 * tid + 0];
        float4 v1 = smem[3 * tid + 1];
        float4 v2 = smem[3 * tid + 2];
        float4 o0, o1, o2;
        xf(M, v0.x, v0.y, v0.z, o0.x, o0.y, o0.z);
        xf(M, v0.w, v1.x, v1.y, o0.w, o1.x, o1.y);
        xf(M, v1.z, v1.w, v2.x, o1.z, o1.w, o2.x);
        xf(M, v2.y, v2.z, v2.w, o2.y, o2.z, o2.w);
        smem[3 * tid + 0] = o0;
        smem[3 * tid + 1] = o1;
        smem[3 * tid + 2] = o2;
        bar_lgkm();   // compute-writes visible to store-phase readers

        // Coalesced LDS -> global CACHED stores, then restage chunk it+1 into
        // the SAME slots (same thread, same address: in-order per wave, no
        // barrier needed between the read and the write).
        float4 s0 = smem[tid];
        float4 s1 = smem[256 + tid];
        float4 s2 = smem[512 + tid];
        out_pcd[base + tid]       = s0;
        out_pcd[base + 256 + tid] = s1;
        out_pcd[base + 512 + tid] = s2;
        if (has_next) {
            smem[tid]       = n0;
            smem[256 + tid] = n1;
            smem[512 + tid] = n2;
        }
        bar_lgkm();   // restage-writes visible to next iteration's compute

        base += (size_t)stride_f4;
    }
}

extern "C" void kernel_launch(void* const* d_in, const int* in_sizes, int n_in,
                              void* d_out, int out_size, void* d_ws, size_t ws_size,
                              hipStream_t stream) {
    const float* pcd   = (const float*)d_in[0];  // (B, N, 3)
    const float* T_mis = (const float*)d_in[1];  // (B, 4, 4)
    const float* q     = (const float*)d_in[2];  // (B, 4)
    const float* t     = (const float*)d_in[3];  // (B, 3)
    float* out = (float*)d_out;

    const int B = in_sizes[2] / 4;                            // 32
    const long long N = (long long)in_sizes[0] / (3LL * B);   // 262144
    const int f4_per_batch = (int)(3 * N / 4);                // 196608
    const int chunks = f4_per_batch / 768;                    // 256

    // 4 chunks per block -> 64 x 32 = 2048 blocks, persistent, no tail.
    int iters = 4;
    if (chunks % 4 != 0) iters = (chunks % 2 == 0) ? 2 : 1;
    const int blocks_x = chunks / iters;                      // 64
    const int stride_f4 = blocks_x * 768;

    // Output layout: [0, B*16) = batch_T_pred; then pcd_new (float4-aligned).
    dim3 grid(blocks_x, B);
    realign_fused_kernel<<<grid, 256, 0, stream>>>(
        (const float4*)pcd, T_mis, q, t,
        out, (float4*)(out + B * 16), f4_per_batch, stride_f4, iters);
}